// Round 8
// baseline (3424.799 us; speedup 1.0000x reference)
//
#include <hip/hip_runtime.h>

#define B_ 256
#define T_ 80
#define IN_ 39
#define H_ 256
#define G_ 1024
#define L_ 5
#define TC_ 16
#define NCH_ 5

#define XP_FLOATS   (B_ * TC_ * G_)     // 4,194,304
#define HBUF_FLOATS (B_ * T_ * H_)      // 5,242,880
#define CBUF_FLOATS (B_ * H_)           // 65,536
#define WG_FLOATS   (L_ * G_ * H_)      // 1,310,720
#define HX_FLOATS   (2 * 32 * 2048)     // 131,072
#define CNT_OFF_FLOATS (XP_FLOATS + HBUF_FLOATS + CBUF_FLOATS + WG_FLOATS + HX_FLOATS)

#define AG __HIP_MEMORY_SCOPE_AGENT

__device__ __forceinline__ float sigm(float x) { return 1.0f / (1.0f + expf(-x)); }
__device__ __forceinline__ void fma4(float4& a, float s, const float4& w) {
    a.x = fmaf(s, w.x, a.x); a.y = fmaf(s, w.y, a.y);
    a.z = fmaf(s, w.z, a.z); a.w = fmaf(s, w.w, a.w);
}
__device__ __forceinline__ void red4(float4& a) {
    a.x += __shfl_xor(a.x, 32); a.y += __shfl_xor(a.y, 32);
    a.z += __shfl_xor(a.z, 32); a.w += __shfl_xor(a.w, 32);
}
__device__ __forceinline__ float lo32(unsigned long long v) { return __uint_as_float((unsigned)v); }
__device__ __forceinline__ float hi32(unsigned long long v) { return __uint_as_float((unsigned)(v >> 32)); }

// ---- Wg: per-slice interleaved W_hh: Wg[l][s][k][j][g] = Whh[l][g*256+s*32+j][k] ----
extern "C" __global__ void __launch_bounds__(256)
wt_kernel(const float* __restrict__ Whh, float* __restrict__ Wg) {
    const int gid = blockIdx.x * 256 + threadIdx.x;
    const int g4 = gid & 3;
    const int j  = (gid >> 2) & 31;
    const int k  = (gid >> 7) & 255;
    const int s  = (gid >> 15) & 7;
    const int l  = gid >> 18;
    Wg[gid] = Whh[((size_t)(l * 1024 + g4 * 256 + s * 32 + j)) * 256 + k];
}

// ---- projection GEMM (layer 0 only now, K=39) ----
extern "C" __global__ void __launch_bounds__(256)
proj_kernel(const float* __restrict__ src, const float* __restrict__ Wih,
            const float* __restrict__ bihl, const float* __restrict__ bhhl,
            float* __restrict__ xp, int K, int t0) {
    __shared__ float As[16 * 68];
    __shared__ float Bs[16 * 68];
    const int tid = threadIdx.x;
    const int mt = blockIdx.x >> 4, nt = blockIdx.x & 15;
    const int tx = tid & 15, ty = tid >> 4;
    const int lr = tid >> 2, lc4 = (tid & 3) << 2;

    const int ar = mt * 64 + lr;
    const int ab = ar >> 4;
    const int at = t0 + (ar & 15);
    const float* arow = src + ((size_t)ab * T_ + at) * K;
    const float* brow = Wih + (size_t)(nt * 64 + lr) * K;

    float acc[4][4];
    #pragma unroll
    for (int i = 0; i < 4; ++i)
        #pragma unroll
        for (int j = 0; j < 4; ++j) acc[i][j] = 0.0f;

    for (int k0 = 0; k0 < K; k0 += 16) {
        __syncthreads();
        if (K == IN_) {
            #pragma unroll
            for (int i = 0; i < 4; ++i) {
                int k = k0 + lc4 + i;
                As[(lc4 + i) * 68 + lr] = (k < IN_) ? arow[k] : 0.0f;
                Bs[(lc4 + i) * 68 + lr] = (k < IN_) ? brow[k] : 0.0f;
            }
        } else {
            float4 av = *(const float4*)(arow + k0 + lc4);
            float4 bv = *(const float4*)(brow + k0 + lc4);
            As[(lc4 + 0) * 68 + lr] = av.x;
            As[(lc4 + 1) * 68 + lr] = av.y;
            As[(lc4 + 2) * 68 + lr] = av.z;
            As[(lc4 + 3) * 68 + lr] = av.w;
            Bs[(lc4 + 0) * 68 + lr] = bv.x;
            Bs[(lc4 + 1) * 68 + lr] = bv.y;
            Bs[(lc4 + 2) * 68 + lr] = bv.z;
            Bs[(lc4 + 3) * 68 + lr] = bv.w;
        }
        __syncthreads();
        #pragma unroll
        for (int kk = 0; kk < 16; ++kk) {
            float4 a4 = *(const float4*)&As[kk * 68 + ty * 4];
            float4 b4 = *(const float4*)&Bs[kk * 68 + tx * 4];
            acc[0][0] += a4.x * b4.x; acc[0][1] += a4.x * b4.y;
            acc[0][2] += a4.x * b4.z; acc[0][3] += a4.x * b4.w;
            acc[1][0] += a4.y * b4.x; acc[1][1] += a4.y * b4.y;
            acc[1][2] += a4.y * b4.z; acc[1][3] += a4.y * b4.w;
            acc[2][0] += a4.z * b4.x; acc[2][1] += a4.z * b4.y;
            acc[2][2] += a4.z * b4.z; acc[2][3] += a4.z * b4.w;
            acc[3][0] += a4.w * b4.x; acc[3][1] += a4.w * b4.y;
            acc[3][2] += a4.w * b4.z; acc[3][3] += a4.w * b4.w;
        }
    }
    const int col = nt * 64 + tx * 4;
    const float bs0 = bihl[col + 0] + bhhl[col + 0];
    const float bs1 = bihl[col + 1] + bhhl[col + 1];
    const float bs2 = bihl[col + 2] + bhhl[col + 2];
    const float bs3 = bihl[col + 3] + bhhl[col + 3];
    #pragma unroll
    for (int i = 0; i < 4; ++i) {
        const int row = mt * 64 + ty * 4 + i;
        float4 o;
        o.x = acc[i][0] + bs0; o.y = acc[i][1] + bs1;
        o.z = acc[i][2] + bs2; o.w = acc[i][3] + bs3;
        *(float4*)&xp[(size_t)row * G_ + col] = o;
    }
}

// ---- fused recurrence + next-chunk projection ----
// Sync scheme = round-4 verbatim (best measured). After publish+bump, phase D
// computes the NEXT chunk's input projection for this block's own (batch,unit)
// cells — no cross-block traffic — filling the sync-propagation bubble.
extern "C" __global__ void __launch_bounds__(512, 2)
rec4_kernel(float* __restrict__ xp, const float* __restrict__ Wg_l,
            float* __restrict__ hbuf, float* __restrict__ cbuf,
            float* __restrict__ hx, int* __restrict__ cnt,
            const float* __restrict__ wih_t, const float* __restrict__ bih_t,
            const float* __restrict__ bhh_t,
            int t0, int chkb, int first, int do_proj, int src_t0) {
    __shared__ float sH[2048];          // hT[k][bb]  (8 KB)
    __shared__ float sA[2048];          // proj source rows, same layout (8 KB)
    __shared__ float sP[8 * 32 * 36];   // part[w][jj][36] (36 KB)

    const int tid = threadIdx.x;
    const int bid = blockIdx.x;
    const int grp = bid & 31;
    const int s   = bid >> 5;
    const int jj  = tid & 31;       // main identity: unit
    const int ks  = tid >> 5;       // main identity: k-slice (0..15)
    const int w   = tid >> 6;       // wave id (0..7)
    const int fb  = (tid >> 5) & 7; // finish identity: batch (tid<256)
    const int fj  = tid & 31;       // finish identity: unit
    const int bglob = grp * 8 + fb;
    const int unit  = s * 32 + fj;
    int* cnt_g = cnt + grp * 32;    // one counter per 128B line

    // rec W fragment (registers)
    const float4* Wg4 = (const float4*)Wg_l + (size_t)s * 8192;
    float4 wreg[16];
    #pragma unroll
    for (int kk = 0; kk < 16; ++kk)
        wreg[kk] = Wg4[(size_t)(ks * 16 + kk) * 32 + jj];

    // proj W fragment (registers) + target bias (finish identity)
    float4 wf[16];
    float pb0 = 0.f, pb1 = 0.f, pb2 = 0.f, pb3 = 0.f;
    if (do_proj) {
        const int pj = s * 32 + jj;
        float4 tg0[4], tg1[4], tg2[4], tg3[4];
        #pragma unroll
        for (int c = 0; c < 4; ++c) {
            tg0[c] = *(const float4*)&wih_t[((size_t)(0 * 256 + pj)) * 256 + ks * 16 + c * 4];
            tg1[c] = *(const float4*)&wih_t[((size_t)(1 * 256 + pj)) * 256 + ks * 16 + c * 4];
            tg2[c] = *(const float4*)&wih_t[((size_t)(2 * 256 + pj)) * 256 + ks * 16 + c * 4];
            tg3[c] = *(const float4*)&wih_t[((size_t)(3 * 256 + pj)) * 256 + ks * 16 + c * 4];
        }
        #pragma unroll
        for (int c = 0; c < 4; ++c) {
            wf[c * 4 + 0] = make_float4(tg0[c].x, tg1[c].x, tg2[c].x, tg3[c].x);
            wf[c * 4 + 1] = make_float4(tg0[c].y, tg1[c].y, tg2[c].y, tg3[c].y);
            wf[c * 4 + 2] = make_float4(tg0[c].z, tg1[c].z, tg2[c].z, tg3[c].z);
            wf[c * 4 + 3] = make_float4(tg0[c].w, tg1[c].w, tg2[c].w, tg3[c].w);
        }
        if (tid < 256) {
            pb0 = bih_t[0 * 256 + unit] + bhh_t[0 * 256 + unit];
            pb1 = bih_t[1 * 256 + unit] + bhh_t[1 * 256 + unit];
            pb2 = bih_t[2 * 256 + unit] + bhh_t[2 * 256 + unit];
            pb3 = bih_t[3 * 256 + unit] + bhh_t[3 * 256 + unit];
        }
    }

    float creg = 0.0f;
    if (tid < 256 && !first) creg = cbuf[(size_t)bglob * H_ + unit];

    const float4* sH4 = (const float4*)sH;
    const float4* sA4 = (const float4*)sA;

    for (int tt = 0; tt < TC_; ++tt) {
        const int t = t0 + tt;

        // ---- phase A: gather h(t-1) into sH ----
        if (tt == 0) {
            if (first) {
                for (int i = tid; i < 2048; i += 512) sH[i] = 0.0f;
            } else if (tid < 256) {
                const int u = tid;
                #pragma unroll
                for (int bb = 0; bb < 8; ++bb)
                    sH[u * 8 + bb] = hbuf[((size_t)(grp * 8 + bb) * T_ + (t0 - 1)) * H_ + u];
            }
        } else {
            if (tid == 0) {
                const int tgt = 8 * (chkb + tt);
                while (__hip_atomic_load(cnt_g, __ATOMIC_RELAXED, AG) < tgt)
                    __builtin_amdgcn_s_sleep(1);
            }
            __syncthreads();
            if (tid < 256) {
                const unsigned long long* hs =
                    (const unsigned long long*)(hx + (size_t)(((tt - 1) & 1) * 32 + grp) * 2048);
                const int u = tid;
                unsigned long long v0 = __hip_atomic_load(hs + u * 4 + 0, __ATOMIC_RELAXED, AG);
                unsigned long long v1 = __hip_atomic_load(hs + u * 4 + 1, __ATOMIC_RELAXED, AG);
                unsigned long long v2 = __hip_atomic_load(hs + u * 4 + 2, __ATOMIC_RELAXED, AG);
                unsigned long long v3 = __hip_atomic_load(hs + u * 4 + 3, __ATOMIC_RELAXED, AG);
                float4 fa, fbv;
                fa.x = lo32(v0); fa.y = hi32(v0); fa.z = lo32(v1); fa.w = hi32(v1);
                fbv.x = lo32(v2); fbv.y = hi32(v2); fbv.z = lo32(v3); fbv.w = hi32(v3);
                *(float4*)&sH[u * 8] = fa;
                *(float4*)&sH[u * 8 + 4] = fbv;
            }
        }

        // xp prefetch (reads OLD value; phase D overwrites later this step)
        float x0 = 0.f, x1 = 0.f, x2 = 0.f, x3 = 0.f;
        if (tid < 256) {
            const size_t xrow = ((size_t)bglob * TC_ + tt) * G_ + unit;
            x0 = xp[xrow];
            x1 = xp[xrow + 256];
            x2 = xp[xrow + 512];
            x3 = xp[xrow + 768];
        }

        __syncthreads();  // B1: sH ready; sP free (prev phase-D readers done)

        // ---- phase B: rec k-loop, W from registers ----
        float4 a0 = {0,0,0,0}, a1 = {0,0,0,0}, a2 = {0,0,0,0}, a3 = {0,0,0,0};
        float4 a4 = {0,0,0,0}, a5 = {0,0,0,0}, a6 = {0,0,0,0}, a7 = {0,0,0,0};
        #pragma unroll
        for (int kk = 0; kk < 16; ++kk) {
            const int k = ks * 16 + kk;
            const float4 wv = wreg[kk];
            const float4 ha = sH4[k * 2];
            const float4 hb = sH4[k * 2 + 1];
            fma4(a0, ha.x, wv); fma4(a1, ha.y, wv);
            fma4(a2, ha.z, wv); fma4(a3, ha.w, wv);
            fma4(a4, hb.x, wv); fma4(a5, hb.y, wv);
            fma4(a6, hb.z, wv); fma4(a7, hb.w, wv);
        }
        red4(a0); red4(a1); red4(a2); red4(a3);
        red4(a4); red4(a5); red4(a6); red4(a7);
        if ((tid & 63) < 32) {
            float4* pp = (float4*)&sP[(w * 32 + jj) * 36];
            pp[0] = a0; pp[1] = a1; pp[2] = a2; pp[3] = a3;
            pp[4] = a4; pp[5] = a5; pp[6] = a6; pp[7] = a7;
        }
        __syncthreads();  // B2: rec partials ready

        // ---- phase C: finish + publish ----
        if (tid < 256) {
            float4 g4;
            g4.x = x0; g4.y = x1; g4.z = x2; g4.w = x3;
            #pragma unroll
            for (int w2 = 0; w2 < 8; ++w2) {
                const float4 pw = *(const float4*)&sP[(w2 * 32 + fj) * 36 + fb * 4];
                g4.x += pw.x; g4.y += pw.y; g4.z += pw.z; g4.w += pw.w;
            }
            const float I = sigm(g4.x);
            const float F = sigm(g4.y);
            const float Gt = tanhf(g4.z);
            const float O = sigm(g4.w);
            creg = F * creg + I * Gt;
            const float hval = O * tanhf(creg);
            hbuf[((size_t)bglob * T_ + t) * H_ + unit] = hval;
            if (tt < TC_ - 1) {
                __hip_atomic_store(hx + (size_t)((tt & 1) * 32 + grp) * 2048 + unit * 8 + fb,
                                   hval, __ATOMIC_RELAXED, AG);
            }
        }
        if (tt < TC_ - 1) {
            asm volatile("s_waitcnt vmcnt(0)" ::: "memory");
            __syncthreads();  // B3: publishes drained; sP free
            if (tid == 0)
                __hip_atomic_fetch_add(cnt_g, 1, __ATOMIC_RELAXED, AG);
        } else if (do_proj) {
            __syncthreads();  // B3': sP free for phase D
        }

        // ---- phase D: next-chunk projection row tt (fills sync bubble) ----
        if (do_proj) {
            if (tid < 256) {
                const int u = tid;
                #pragma unroll
                for (int bb = 0; bb < 8; ++bb)
                    sA[u * 8 + bb] =
                        hbuf[((size_t)(grp * 8 + bb) * T_ + (src_t0 + tt)) * H_ + u];
            }
            __syncthreads();  // B4: sA ready
            float4 p0 = {0,0,0,0}, p1 = {0,0,0,0}, p2 = {0,0,0,0}, p3 = {0,0,0,0};
            float4 p4 = {0,0,0,0}, p5 = {0,0,0,0}, p6 = {0,0,0,0}, p7 = {0,0,0,0};
            #pragma unroll
            for (int kk = 0; kk < 16; ++kk) {
                const int k = ks * 16 + kk;
                const float4 wv = wf[kk];
                const float4 ha = sA4[k * 2];
                const float4 hb = sA4[k * 2 + 1];
                fma4(p0, ha.x, wv); fma4(p1, ha.y, wv);
                fma4(p2, ha.z, wv); fma4(p3, ha.w, wv);
                fma4(p4, hb.x, wv); fma4(p5, hb.y, wv);
                fma4(p6, hb.z, wv); fma4(p7, hb.w, wv);
            }
            red4(p0); red4(p1); red4(p2); red4(p3);
            red4(p4); red4(p5); red4(p6); red4(p7);
            if ((tid & 63) < 32) {
                float4* pp = (float4*)&sP[(w * 32 + jj) * 36];
                pp[0] = p0; pp[1] = p1; pp[2] = p2; pp[3] = p3;
                pp[4] = p4; pp[5] = p5; pp[6] = p6; pp[7] = p7;
            }
            __syncthreads();  // B5: proj partials ready
            if (tid < 256) {
                float4 g4;
                g4.x = pb0; g4.y = pb1; g4.z = pb2; g4.w = pb3;
                #pragma unroll
                for (int w2 = 0; w2 < 8; ++w2) {
                    const float4 pw = *(const float4*)&sP[(w2 * 32 + fj) * 36 + fb * 4];
                    g4.x += pw.x; g4.y += pw.y; g4.z += pw.z; g4.w += pw.w;
                }
                const size_t xrow = ((size_t)bglob * TC_ + tt) * G_ + unit;
                xp[xrow]       = g4.x;
                xp[xrow + 256] = g4.y;
                xp[xrow + 512] = g4.z;
                xp[xrow + 768] = g4.w;
            }
            // next iteration's B1 barrier protects sP reuse
        }
    }

    if (tid < 256) cbuf[(size_t)bglob * H_ + unit] = creg;
}

// ---- final FC ----
extern "C" __global__ void __launch_bounds__(128)
fc_kernel(const float* __restrict__ hbuf, const float* __restrict__ fcw,
          const float* __restrict__ fcb, float* __restrict__ out) {
    __shared__ float wsm[256];
    const int tid = threadIdx.x;
    const int b = blockIdx.x;
    if (tid < 64) ((float4*)wsm)[tid] = ((const float4*)fcw)[tid];
    __syncthreads();
    if (tid < T_) {
        const float4* h4p = (const float4*)(hbuf + ((size_t)b * T_ + tid) * H_);
        const float4* w4p = (const float4*)wsm;
        float acc = fcb[0];
        #pragma unroll 8
        for (int k4 = 0; k4 < 64; ++k4) {
            float4 h4 = h4p[k4], w4 = w4p[k4];
            acc += h4.x * w4.x + h4.y * w4.y + h4.z * w4.z + h4.w * w4.w;
        }
        out[b * T_ + tid] = acc;
    }
}

extern "C" void kernel_launch(void* const* d_in, const int* in_sizes, int n_in,
                              void* d_out, int out_size, void* d_ws, size_t ws_size,
                              hipStream_t stream) {
    (void)in_sizes; (void)n_in; (void)out_size; (void)ws_size;
    const float* x    = (const float*)d_in[0];
    const float* Wih0 = (const float*)d_in[1];
    const float* Wihr = (const float*)d_in[2];
    const float* Whh  = (const float*)d_in[3];
    const float* bih  = (const float*)d_in[4];
    const float* bhh  = (const float*)d_in[5];
    const float* fcw  = (const float*)d_in[6];
    const float* fcb  = (const float*)d_in[7];
    float* out = (float*)d_out;
    float* ws  = (float*)d_ws;

    float* xp   = ws;
    float* hbuf = ws + XP_FLOATS;
    float* cbuf = hbuf + HBUF_FLOATS;
    float* wg   = cbuf + CBUF_FLOATS;
    float* hx   = wg + WG_FLOATS;
    int*   cnt  = (int*)(ws + CNT_OFF_FLOATS);

    hipMemsetAsync(cnt, 0, 32 * 32 * sizeof(int), stream);
    hipLaunchKernelGGL(wt_kernel, dim3(WG_FLOATS / 256), dim3(256), 0, stream, Whh, wg);

    for (int l = 0; l < L_; ++l) {
        const float* Wg_l = wg + (size_t)l * (G_ * H_);
        for (int ch = 0; ch < NCH_; ++ch) {
            const int t0 = ch * TC_;
            const int gc = l * NCH_ + ch;
            const int chkb = gc * (TC_ - 1);
            if (l == 0) {
                hipLaunchKernelGGL(proj_kernel, dim3(1024), dim3(256), 0, stream,
                                   x, Wih0, bih, bhh, xp, IN_, t0);
            }
            int lt, do_proj;
            if (ch < NCH_ - 1) { lt = l;     do_proj = (l >= 1) ? 1 : 0; }
            else               { lt = l + 1; do_proj = (lt <= L_ - 1) ? 1 : 0; }
            const int ltc = do_proj ? lt : 1;   // clamp for pointer math when unused
            const float* wih_t = Wihr + (size_t)(ltc - 1) * G_ * H_;
            const float* biht  = bih + ltc * G_;
            const float* bhht  = bhh + ltc * G_;
            const int src_t0 = (ch < NCH_ - 1) ? (t0 + TC_) : 0;
            hipLaunchKernelGGL(rec4_kernel, dim3(256), dim3(512), 0, stream,
                               xp, Wg_l, hbuf, cbuf, hx, cnt,
                               wih_t, biht, bhht,
                               t0, chkb, ch == 0 ? 1 : 0, do_proj, src_t0);
        }
    }
    hipLaunchKernelGGL(fc_kernel, dim3(B_), dim3(128), 0, stream, hbuf, fcw, fcb, out);
}

// Round 9
// 2581.580 us; speedup vs baseline: 1.3266x; 1.3266x over previous
//
#include <hip/hip_runtime.h>

#define B_ 256
#define T_ 80
#define IN_ 39
#define H_ 256
#define G_ 1024
#define L_ 5
#define TC_ 16
#define NCH_ 5

#define XP_FLOATS   (B_ * TC_ * G_)     // 4,194,304
#define HBUF_FLOATS (B_ * T_ * H_)      // 5,242,880
#define CBUF_FLOATS (B_ * H_)           // 65,536
#define WG_FLOATS   (L_ * G_ * H_)      // 1,310,720
#define HX_FLOATS   (2 * 32 * 2048)     // 131,072
#define FLG_OFF_FLOATS (XP_FLOATS + HBUF_FLOATS + CBUF_FLOATS + WG_FLOATS + HX_FLOATS)

#define AG __HIP_MEMORY_SCOPE_AGENT

__device__ __forceinline__ float sigm(float x) { return 1.0f / (1.0f + expf(-x)); }
__device__ __forceinline__ void fma4(float4& a, float s, const float4& w) {
    a.x = fmaf(s, w.x, a.x); a.y = fmaf(s, w.y, a.y);
    a.z = fmaf(s, w.z, a.z); a.w = fmaf(s, w.w, a.w);
}
__device__ __forceinline__ void red4(float4& a) {
    a.x += __shfl_xor(a.x, 32); a.y += __shfl_xor(a.y, 32);
    a.z += __shfl_xor(a.z, 32); a.w += __shfl_xor(a.w, 32);
}
__device__ __forceinline__ float lo32(unsigned long long v) { return __uint_as_float((unsigned)v); }
__device__ __forceinline__ float hi32(unsigned long long v) { return __uint_as_float((unsigned)(v >> 32)); }

// ---- Wg: per-slice interleaved W_hh: Wg[l][s][k][j][g] = Whh[l][g*256+s*32+j][k] ----
extern "C" __global__ void __launch_bounds__(256)
wt_kernel(const float* __restrict__ Whh, float* __restrict__ Wg) {
    const int gid = blockIdx.x * 256 + threadIdx.x;
    const int g4 = gid & 3;
    const int j  = (gid >> 2) & 31;
    const int k  = (gid >> 7) & 255;
    const int s  = (gid >> 15) & 7;
    const int l  = gid >> 18;
    Wg[gid] = Whh[((size_t)(l * 1024 + g4 * 256 + s * 32 + j)) * 256 + k];
}

// ---- projection GEMM (unchanged, all 25 chunks) ----
extern "C" __global__ void __launch_bounds__(256)
proj_kernel(const float* __restrict__ src, const float* __restrict__ Wih,
            const float* __restrict__ bihl, const float* __restrict__ bhhl,
            float* __restrict__ xp, int K, int t0) {
    __shared__ float As[16 * 68];
    __shared__ float Bs[16 * 68];
    const int tid = threadIdx.x;
    const int mt = blockIdx.x >> 4, nt = blockIdx.x & 15;
    const int tx = tid & 15, ty = tid >> 4;
    const int lr = tid >> 2, lc4 = (tid & 3) << 2;

    const int ar = mt * 64 + lr;
    const int ab = ar >> 4;
    const int at = t0 + (ar & 15);
    const float* arow = src + ((size_t)ab * T_ + at) * K;
    const float* brow = Wih + (size_t)(nt * 64 + lr) * K;

    float acc[4][4];
    #pragma unroll
    for (int i = 0; i < 4; ++i)
        #pragma unroll
        for (int j = 0; j < 4; ++j) acc[i][j] = 0.0f;

    for (int k0 = 0; k0 < K; k0 += 16) {
        __syncthreads();
        if (K == IN_) {
            #pragma unroll
            for (int i = 0; i < 4; ++i) {
                int k = k0 + lc4 + i;
                As[(lc4 + i) * 68 + lr] = (k < IN_) ? arow[k] : 0.0f;
                Bs[(lc4 + i) * 68 + lr] = (k < IN_) ? brow[k] : 0.0f;
            }
        } else {
            float4 av = *(const float4*)(arow + k0 + lc4);
            float4 bv = *(const float4*)(brow + k0 + lc4);
            As[(lc4 + 0) * 68 + lr] = av.x;
            As[(lc4 + 1) * 68 + lr] = av.y;
            As[(lc4 + 2) * 68 + lr] = av.z;
            As[(lc4 + 3) * 68 + lr] = av.w;
            Bs[(lc4 + 0) * 68 + lr] = bv.x;
            Bs[(lc4 + 1) * 68 + lr] = bv.y;
            Bs[(lc4 + 2) * 68 + lr] = bv.z;
            Bs[(lc4 + 3) * 68 + lr] = bv.w;
        }
        __syncthreads();
        #pragma unroll
        for (int kk = 0; kk < 16; ++kk) {
            float4 a4 = *(const float4*)&As[kk * 68 + ty * 4];
            float4 b4 = *(const float4*)&Bs[kk * 68 + tx * 4];
            acc[0][0] += a4.x * b4.x; acc[0][1] += a4.x * b4.y;
            acc[0][2] += a4.x * b4.z; acc[0][3] += a4.x * b4.w;
            acc[1][0] += a4.y * b4.x; acc[1][1] += a4.y * b4.y;
            acc[1][2] += a4.y * b4.z; acc[1][3] += a4.y * b4.w;
            acc[2][0] += a4.z * b4.x; acc[2][1] += a4.z * b4.y;
            acc[2][2] += a4.z * b4.z; acc[2][3] += a4.z * b4.w;
            acc[3][0] += a4.w * b4.x; acc[3][1] += a4.w * b4.y;
            acc[3][2] += a4.w * b4.z; acc[3][3] += a4.w * b4.w;
        }
    }
    const int col = nt * 64 + tx * 4;
    const float bs0 = bihl[col + 0] + bhhl[col + 0];
    const float bs1 = bihl[col + 1] + bhhl[col + 1];
    const float bs2 = bihl[col + 2] + bhhl[col + 2];
    const float bs3 = bihl[col + 3] + bhhl[col + 3];
    #pragma unroll
    for (int i = 0; i < 4; ++i) {
        const int row = mt * 64 + ty * 4 + i;
        float4 o;
        o.x = acc[i][0] + bs0; o.y = acc[i][1] + bs1;
        o.z = acc[i][2] + bs2; o.w = acc[i][3] + bs3;
        *(float4*)&xp[(size_t)row * G_ + col] = o;
    }
}

// ---- recurrence: W in registers, 512 threads; per-slice FLAG-STORE sync ----
// vs round 7 (best): the shared fetch_add counter (8 RMWs/step serializing on
// one MALL line) is replaced by 8 per-slice flag words — producer tid0 does a
// plain relaxed agent-scope STORE of the step id into its own word (ordering
// still enforced by vmcnt(0) drain + barrier before it); consumers poll with
// 8 scout threads, one flag each. xp prefetch hoisted above the poll so its
// latency hides under the wait.
extern "C" __global__ void __launch_bounds__(512, 2)
rec5_kernel(const float* __restrict__ xp, const float* __restrict__ Wg_l,
            float* __restrict__ hbuf, float* __restrict__ cbuf,
            float* __restrict__ hx, int* __restrict__ flg,
            int t0, int chkb, int first) {
    __shared__ float sH[2048];          // hT[k][bb]  (8 KB)
    __shared__ float sP[8 * 32 * 36];   // part[w][jj][36] (36 KB)

    const int tid = threadIdx.x;
    const int bid = blockIdx.x;
    const int grp = bid & 31;
    const int s   = bid >> 5;
    const int jj  = tid & 31;       // main identity: unit
    const int ks  = tid >> 5;       // main identity: k-slice (0..15)
    const int w   = tid >> 6;       // wave id (0..7)
    const int fb  = (tid >> 5) & 7; // finish identity: batch (tid<256)
    const int fj  = tid & 31;       // finish identity: unit
    const int bglob = grp * 8 + fb;
    const int unit  = s * 32 + fj;
    int* flg_g = flg + grp * 32;    // group's 128B line; words 0..7 = slices

    // W fragment into registers: wreg[kk] = 4 gates of unit jj at k = ks*16+kk
    const float4* Wg4 = (const float4*)Wg_l + (size_t)s * 8192;
    float4 wreg[16];
    #pragma unroll
    for (int kk = 0; kk < 16; ++kk)
        wreg[kk] = Wg4[(size_t)(ks * 16 + kk) * 32 + jj];

    float creg = 0.0f;
    if (tid < 256 && !first) creg = cbuf[(size_t)bglob * H_ + unit];

    const float4* sH4 = (const float4*)sH;

    for (int tt = 0; tt < TC_; ++tt) {
        const int t = t0 + tt;

        // xp prefetch FIRST (independent of peers; hides under the poll)
        float x0 = 0.f, x1 = 0.f, x2 = 0.f, x3 = 0.f;
        if (tid < 256) {
            const size_t xrow = ((size_t)bglob * TC_ + tt) * G_ + unit;
            x0 = xp[xrow];
            x1 = xp[xrow + 256];
            x2 = xp[xrow + 512];
            x3 = xp[xrow + 768];
        }

        // ---- phase A: gather h(t-1) into sH (hT[k][bb]) ----
        if (tt == 0) {
            if (first) {
                for (int i = tid; i < 2048; i += 512) sH[i] = 0.0f;
            } else if (tid < 256) {
                const int u = tid;
                #pragma unroll
                for (int bb = 0; bb < 8; ++bb)
                    sH[u * 8 + bb] = hbuf[((size_t)(grp * 8 + bb) * T_ + (t0 - 1)) * H_ + u];
            }
        } else {
            if (tid < 8) {                  // scouts: one flag per slice
                const int tgt = chkb + tt;
                while (__hip_atomic_load(flg_g + tid, __ATOMIC_RELAXED, AG) < tgt)
                    __builtin_amdgcn_s_sleep(1);
            }
            __syncthreads();
            if (tid < 256) {
                const unsigned long long* hs =
                    (const unsigned long long*)(hx + (size_t)(((tt - 1) & 1) * 32 + grp) * 2048);
                const int u = tid;
                unsigned long long v0 = __hip_atomic_load(hs + u * 4 + 0, __ATOMIC_RELAXED, AG);
                unsigned long long v1 = __hip_atomic_load(hs + u * 4 + 1, __ATOMIC_RELAXED, AG);
                unsigned long long v2 = __hip_atomic_load(hs + u * 4 + 2, __ATOMIC_RELAXED, AG);
                unsigned long long v3 = __hip_atomic_load(hs + u * 4 + 3, __ATOMIC_RELAXED, AG);
                float4 fa, fbv;
                fa.x = lo32(v0); fa.y = hi32(v0); fa.z = lo32(v1); fa.w = hi32(v1);
                fbv.x = lo32(v2); fbv.y = hi32(v2); fbv.z = lo32(v3); fbv.w = hi32(v3);
                *(float4*)&sH[u * 8] = fa;
                *(float4*)&sH[u * 8 + 4] = fbv;
            }
        }

        __syncthreads();  // (b) sH ready

        // ---- phase B: k-loop, W from registers, h broadcast from LDS ----
        float4 a0 = {0,0,0,0}, a1 = {0,0,0,0}, a2 = {0,0,0,0}, a3 = {0,0,0,0};
        float4 a4 = {0,0,0,0}, a5 = {0,0,0,0}, a6 = {0,0,0,0}, a7 = {0,0,0,0};
        #pragma unroll
        for (int kk = 0; kk < 16; ++kk) {
            const int k = ks * 16 + kk;
            const float4 wv = wreg[kk];
            const float4 ha = sH4[k * 2];
            const float4 hb = sH4[k * 2 + 1];
            fma4(a0, ha.x, wv); fma4(a1, ha.y, wv);
            fma4(a2, ha.z, wv); fma4(a3, ha.w, wv);
            fma4(a4, hb.x, wv); fma4(a5, hb.y, wv);
            fma4(a6, hb.z, wv); fma4(a7, hb.w, wv);
        }
        red4(a0); red4(a1); red4(a2); red4(a3);
        red4(a4); red4(a5); red4(a6); red4(a7);
        if ((tid & 63) < 32) {
            float4* pp = (float4*)&sP[(w * 32 + jj) * 36];
            pp[0] = a0; pp[1] = a1; pp[2] = a2; pp[3] = a3;
            pp[4] = a4; pp[5] = a5; pp[6] = a6; pp[7] = a7;
        }
        __syncthreads();  // (c) partials ready

        // ---- phase C: finish (tid < 256) ----
        if (tid < 256) {
            float4 g4;
            g4.x = x0; g4.y = x1; g4.z = x2; g4.w = x3;
            #pragma unroll
            for (int w2 = 0; w2 < 8; ++w2) {
                const float4 pw = *(const float4*)&sP[(w2 * 32 + fj) * 36 + fb * 4];
                g4.x += pw.x; g4.y += pw.y; g4.z += pw.z; g4.w += pw.w;
            }
            const float I = sigm(g4.x);
            const float F = sigm(g4.y);
            const float Gt = tanhf(g4.z);
            const float O = sigm(g4.w);
            creg = F * creg + I * Gt;
            const float hval = O * tanhf(creg);
            hbuf[((size_t)bglob * T_ + t) * H_ + unit] = hval;

            if (tt < TC_ - 1) {
                __hip_atomic_store(hx + (size_t)((tt & 1) * 32 + grp) * 2048 + unit * 8 + fb,
                                   hval, __ATOMIC_RELAXED, AG);
            }
        }

        if (tt < TC_ - 1) {
            asm volatile("s_waitcnt vmcnt(0)" ::: "memory");
            __syncthreads();  // (d) all publishes drained
            if (tid == 0)     // plain store, own word: no RMW serialization
                __hip_atomic_store(flg_g + s, chkb + tt + 1, __ATOMIC_RELAXED, AG);
        }
    }

    if (tid < 256) cbuf[(size_t)bglob * H_ + unit] = creg;
}

// ---- final FC ----
extern "C" __global__ void __launch_bounds__(128)
fc_kernel(const float* __restrict__ hbuf, const float* __restrict__ fcw,
          const float* __restrict__ fcb, float* __restrict__ out) {
    __shared__ float wsm[256];
    const int tid = threadIdx.x;
    const int b = blockIdx.x;
    if (tid < 64) ((float4*)wsm)[tid] = ((const float4*)fcw)[tid];
    __syncthreads();
    if (tid < T_) {
        const float4* h4p = (const float4*)(hbuf + ((size_t)b * T_ + tid) * H_);
        const float4* w4p = (const float4*)wsm;
        float acc = fcb[0];
        #pragma unroll 8
        for (int k4 = 0; k4 < 64; ++k4) {
            float4 h4 = h4p[k4], w4 = w4p[k4];
            acc += h4.x * w4.x + h4.y * w4.y + h4.z * w4.z + h4.w * w4.w;
        }
        out[b * T_ + tid] = acc;
    }
}

extern "C" void kernel_launch(void* const* d_in, const int* in_sizes, int n_in,
                              void* d_out, int out_size, void* d_ws, size_t ws_size,
                              hipStream_t stream) {
    (void)in_sizes; (void)n_in; (void)out_size; (void)ws_size;
    const float* x    = (const float*)d_in[0];
    const float* Wih0 = (const float*)d_in[1];
    const float* Wihr = (const float*)d_in[2];
    const float* Whh  = (const float*)d_in[3];
    const float* bih  = (const float*)d_in[4];
    const float* bhh  = (const float*)d_in[5];
    const float* fcw  = (const float*)d_in[6];
    const float* fcb  = (const float*)d_in[7];
    float* out = (float*)d_out;
    float* ws  = (float*)d_ws;

    float* xp   = ws;
    float* hbuf = ws + XP_FLOATS;
    float* cbuf = hbuf + HBUF_FLOATS;
    float* wg   = cbuf + CBUF_FLOATS;
    float* hx   = wg + WG_FLOATS;
    int*   flg  = (int*)(ws + FLG_OFF_FLOATS);

    hipMemsetAsync(flg, 0, 32 * 32 * sizeof(int), stream);
    hipLaunchKernelGGL(wt_kernel, dim3(WG_FLOATS / 256), dim3(256), 0, stream, Whh, wg);

    for (int l = 0; l < L_; ++l) {
        const int K = (l == 0) ? IN_ : H_;
        const float* src = (l == 0) ? x : hbuf;
        const float* Wih = (l == 0) ? Wih0 : (Wihr + (size_t)(l - 1) * G_ * H_);
        const float* Wg_l = wg + (size_t)l * (G_ * H_);
        for (int ch = 0; ch < NCH_; ++ch) {
            const int t0 = ch * TC_;
            const int chkb = (l * NCH_ + ch) * (TC_ - 1);
            hipLaunchKernelGGL(proj_kernel, dim3(1024), dim3(256), 0, stream,
                               src, Wih, bih + l * G_, bhh + l * G_, xp, K, t0);
            hipLaunchKernelGGL(rec5_kernel, dim3(256), dim3(512), 0, stream,
                               xp, Wg_l, hbuf, cbuf, hx, flg, t0, chkb, ch == 0 ? 1 : 0);
        }
    }
    hipLaunchKernelGGL(fc_kernel, dim3(B_), dim3(128), 0, stream, hbuf, fcw, fcb, out);
}